// Round 3
// baseline (68.411 us; speedup 1.0000x reference)
//
#include <hip/hip_runtime.h>

#define BB 4
#define TT 2048
#define DD 1024
#define EE 8
#define CAP 512
#define NTOK (BB*TT)
#define OUT_HALF ((size_t)NTOK * EE * CAP)   // 33,554,432 floats per tensor

// ---------------- Kernel 1: gating ----------------
// grid = 2048 blocks x 256 threads. One wave (64 lanes) per token.
// float4 loads for x and w (w: 32KB, L1/L2-resident).
// Writes: e0 = top1 expert, e1enc = top2 expert | (route<<3), v0/v1 = renorm gates.
__global__ __launch_bounds__(256) void gate_kernel(
    const float* __restrict__ x, const float* __restrict__ w,
    const float* __restrict__ probs,
    int* __restrict__ e0, int* __restrict__ e1enc,
    float* __restrict__ v0, float* __restrict__ v1)
{
    const int wave = threadIdx.x >> 6;
    const int lane = threadIdx.x & 63;
    const int token = blockIdx.x * 4 + wave;   // token = b*TT + t
    const float4* xt4 = (const float4*)(x + (size_t)token * DD);
    const float4* w4  = (const float4*)w;

    float acc[EE];
    #pragma unroll
    for (int e = 0; e < EE; ++e) acc[e] = 0.f;

    #pragma unroll
    for (int i = 0; i < 4; ++i) {
        float4 xv = xt4[i * 64 + lane];
        #pragma unroll
        for (int e = 0; e < EE; ++e) {
            float4 wv = w4[e * 256 + i * 64 + lane];
            acc[e] = fmaf(xv.x, wv.x, acc[e]);
            acc[e] = fmaf(xv.y, wv.y, acc[e]);
            acc[e] = fmaf(xv.z, wv.z, acc[e]);
            acc[e] = fmaf(xv.w, wv.w, acc[e]);
        }
    }
    #pragma unroll
    for (int e = 0; e < EE; ++e) {
        #pragma unroll
        for (int off = 32; off > 0; off >>= 1)
            acc[e] += __shfl_xor(acc[e], off, 64);
    }

    if (lane == 0) {
        float mx = acc[0];
        #pragma unroll
        for (int e = 1; e < EE; ++e) mx = fmaxf(mx, acc[e]);
        float ex[EE]; float Z = 0.f;
        #pragma unroll
        for (int e = 0; e < EE; ++e) { ex[e] = expf(acc[e] - mx); Z += ex[e]; }
        int i0 = 0;
        #pragma unroll
        for (int e = 1; e < EE; ++e) if (ex[e] > ex[i0]) i0 = e;
        int i1 = (i0 == 0) ? 1 : 0;
        #pragma unroll
        for (int e = 0; e < EE; ++e) if (e != i0 && ex[e] > ex[i1]) i1 = e;
        float t0 = ex[i0] / Z, t1 = ex[i1] / Z;
        float den = fmaxf(t0 + t1, 1e-9f);
        float g0 = t0 / den, g1 = t1 / den;
        float p1 = probs[NTOK + token];
        int route = (p1 < g1 / 0.2f) ? 1 : 0;
        e0[token] = i0;
        e1enc[token] = i1 | (route << 3);
        v0[token] = g0; v1[token] = g1;
    }
}

// ---------------- Kernel 2: capacity scan, one wave per (batch, expert) ------
// grid = 32 blocks x 64 threads. No LDS, no __syncthreads. Each wave preloads
// its batch's 2048 expert choices into registers, then 32 ballot rounds per
// rank with a scalar running count. Writes flat targets (e*CAP+pos or -1).
__global__ __launch_bounds__(64) void scan_kernel(
    const int* __restrict__ e0, const int* __restrict__ e1enc,
    int* __restrict__ t0, int* __restrict__ t1)
{
    const int b = blockIdx.x >> 3;
    const int e = blockIdx.x & 7;
    const int lane = threadIdx.x;
    const unsigned long long lt = (lane == 63) ? 0x7fffffffffffffffull
                                               : ((1ull << lane) - 1ull);
    const int base_tok = b * TT;

    // ---- rank 0 ----
    int ev[32];
    #pragma unroll
    for (int c = 0; c < 32; ++c) ev[c] = e0[base_tok + c * 64 + lane];

    int cnt = 0;
    #pragma unroll
    for (int c = 0; c < 32; ++c) {
        bool hit = (ev[c] == e);
        unsigned long long m = __ballot(hit);
        if (hit) {
            int pos = cnt + __popcll(m & lt);
            t0[base_tok + c * 64 + lane] = (pos < CAP) ? e * CAP + pos : -1;
        }
        cnt += __popcll(m);
    }

    // ---- rank 1 (prev = min(cnt, CAP)) ----
    int e1v[32];
    #pragma unroll
    for (int c = 0; c < 32; ++c) e1v[c] = e1enc[base_tok + c * 64 + lane];

    int cnt1 = min(cnt, CAP);
    #pragma unroll
    for (int c = 0; c < 32; ++c) {
        bool sel = ((e1v[c] & 7) == e);           // this wave owns the write
        bool hit = sel && (e1v[c] & 8);           // actually routed
        unsigned long long m = __ballot(hit);
        if (sel) {
            int pos = cnt1 + __popcll(m & lt);
            t1[base_tok + c * 64 + lane] = (hit && pos < CAP) ? e * CAP + pos : -1;
        }
        cnt1 += __popcll(m);
    }
}

// ---------------- Kernel 3: fused zero-fill + scatter (pure streaming) -------
// grid = 8192 blocks (one per token) x 256 threads. Each block writes the
// token's [E,C]=4096-float row in BOTH tensors: 2048 float4 coalesced stores,
// nonzeros inserted branchlessly via per-component compares.
__global__ __launch_bounds__(256) void fill_scatter_kernel(
    const int* __restrict__ t0, const int* __restrict__ t1,
    const float* __restrict__ v0, const float* __restrict__ v1,
    float4* __restrict__ out)
{
    const int token = blockIdx.x;
    const int tid = threadIdx.x;
    const int a0 = t0[token];
    const int a1 = t1[token];
    const float g0 = v0[token];
    const float g1 = v1[token];

    float4* drow = out + (size_t)token * 1024;                  // dispatch row
    float4* crow = out + (OUT_HALF / 4) + (size_t)token * 1024; // combine row

    #pragma unroll
    for (int i = 0; i < 4; ++i) {
        const int f = i * 1024 + tid * 4;   // flat float index within row
        float4 d, c;
        d.x = (f + 0 == a0 || f + 0 == a1) ? 1.f : 0.f;
        d.y = (f + 1 == a0 || f + 1 == a1) ? 1.f : 0.f;
        d.z = (f + 2 == a0 || f + 2 == a1) ? 1.f : 0.f;
        d.w = (f + 3 == a0 || f + 3 == a1) ? 1.f : 0.f;
        c.x = (f + 0 == a0) ? g0 : ((f + 0 == a1) ? g1 : 0.f);
        c.y = (f + 1 == a0) ? g0 : ((f + 1 == a1) ? g1 : 0.f);
        c.z = (f + 2 == a0) ? g0 : ((f + 2 == a1) ? g1 : 0.f);
        c.w = (f + 3 == a0) ? g0 : ((f + 3 == a1) ? g1 : 0.f);
        drow[i * 256 + tid] = d;
        crow[i * 256 + tid] = c;
    }
}

extern "C" void kernel_launch(void* const* d_in, const int* in_sizes, int n_in,
                              void* d_out, int out_size, void* d_ws, size_t ws_size,
                              hipStream_t stream) {
    const float* x     = (const float*)d_in[0];
    const float* w     = (const float*)d_in[1];
    const float* probs = (const float*)d_in[2];
    float* out = (float*)d_out;

    int*   e0 = (int*)d_ws;
    int*   e1 = e0 + NTOK;
    int*   t0 = e1 + NTOK;
    int*   t1 = t0 + NTOK;
    float* v0 = (float*)(t1 + NTOK);
    float* v1 = v0 + NTOK;

    gate_kernel<<<2048, 256, 0, stream>>>(x, w, probs, e0, e1, v0, v1);
    scan_kernel<<<32, 64, 0, stream>>>(e0, e1, t0, t1);
    fill_scatter_kernel<<<8192, 256, 0, stream>>>(t0, t1, v0, v1, (float4*)out);
}